// Round 14
// baseline (242.725 us; speedup 1.0000x reference)
//
#include <hip/hip_runtime.h>
#include <cstdint>
#include <cstddef>

// CNLinkPredictor on MI355X — round 14: ONE kernel, producer/consumer flags.
// 256 blocks x 1024 thr, LDS 101KB => exactly 1 block/CU => all 256 blocks
// co-resident from dispatch (deadlock-free without cooperative API).
//   per block: [bid<48: weight tile -> frag-major bf16-hi planes; fence; wctr++]
//              bitmask slice (contiguous 1MB of adj, ballot); fence; bctr++
//              P1 stage xij -> B planes            (rides under adj stream)
//              spin wctr==48  -> P2 XIJ -> regs    (rides under adj stream)
//              spin bctr==256 -> scan -> on-demand H chunks -> xcn regs
//              -> T2 -> z(beta)+xijr -> lin1+gemv -> out
// Sync: device-scope atomics + __threadfence (G16 pattern); s_sleep spin.
// Counters zeroed per launch via hipMemsetAsync (graph-capture safe).
// Math = round 13: split-bf16 activations x bf16-hi weights, 2 MFMAs/pair,
// absmax 1.95e-3 (threshold 9.77e-3). LDS planes [32][256], chunk-XOR
// swizzle (c8 ^= row&7); weights frag-major, one 16B load/lane/frag.

#define C_DIM   256
#define N_NODES 8192
#define E_EDGES 8192

typedef short bf16x8 __attribute__((ext_vector_type(8)));
typedef float f32x4  __attribute__((ext_vector_type(4)));

struct WPtrs { const float* p[6]; };

__device__ __forceinline__ unsigned short bf16_rne(float a) {
    unsigned u = __float_as_uint(a);
    u += 0x7FFFu + ((u >> 16) & 1u);
    return (unsigned short)(u >> 16);
}
__device__ __forceinline__ void split2(float v, short& h, short& l) {
    unsigned short hb = bf16_rne(v);
    h = (short)hb;
    l = (short)bf16_rne(v - __uint_as_float((unsigned)hb << 16));
}

__device__ __forceinline__ void block_signal(unsigned* c) {
    __syncthreads();
    if (threadIdx.x == 0) {
        __threadfence();
        __hip_atomic_fetch_add(c, 1u, __ATOMIC_RELEASE, __HIP_MEMORY_SCOPE_AGENT);
    }
}
__device__ __forceinline__ void block_wait(const unsigned* c, unsigned tgt) {
    if (threadIdx.x == 0) {
        while (__hip_atomic_load(c, __ATOMIC_ACQUIRE, __HIP_MEMORY_SCOPE_AGENT) < tgt)
            __builtin_amdgcn_s_sleep(32);
    }
    __syncthreads();
    __threadfence();
}

// ---- split-act x bf16-hi-weight layer core: acc[2] = IN(32x256) @ Whi ----
__device__ __forceinline__ void layer_core(
    const short (*INH)[C_DIM], const short (*INL)[C_DIM],
    const short* __restrict__ WH, f32x4 acc[2])
{
    const int t = threadIdx.x, lane = t & 63, wq = t >> 6;   // 16 waves
    const int fr = lane & 15, q = lane >> 4;
    #pragma unroll
    for (int i = 0; i < 2; ++i)
        #pragma unroll
        for (int r = 0; r < 4; ++r) acc[i][r] = 0.f;
    #pragma unroll 2
    for (int kf = 0; kf < 8; ++kf) {
        bf16x8 aH[2], aL[2];
        #pragma unroll
        for (int mf = 0; mf < 2; ++mf) {
            const int row = mf * 16 + fr;
            const int cc = (((kf << 2) + q) ^ (row & 7)) << 3;
            aH[mf] = *(const bf16x8*)&INH[row][cc];
            aL[mf] = *(const bf16x8*)&INL[row][cc];
        }
        const int wo = (((kf << 4) + wq) * 64 + lane) * 8;
        bf16x8 bH = *(const bf16x8*)&WH[wo];
        #pragma unroll
        for (int mf = 0; mf < 2; ++mf) {
            acc[mf] = __builtin_amdgcn_mfma_f32_16x16x32_bf16(aH[mf], bH, acc[mf], 0, 0, 0);
            acc[mf] = __builtin_amdgcn_mfma_f32_16x16x32_bf16(aL[mf], bH, acc[mf], 0, 0, 0);
        }
    }
}

__global__ __launch_bounds__(1024, 1) void k_all(
    const float* __restrict__ adj, const float* __restrict__ x,
    const int* __restrict__ tar, WPtrs wp,
    unsigned long long* __restrict__ bits, short* __restrict__ WFH,
    unsigned* __restrict__ ctrs,
    const float* __restrict__ b1x, const float* __restrict__ b2x,
    const float* __restrict__ bxij, const float* __restrict__ bcn1,
    const float* __restrict__ bcn2, const float* __restrict__ blin1,
    const float* __restrict__ betap, const float* __restrict__ w2,
    const float* __restrict__ b2o, float* __restrict__ out)
{
    __shared__ float wtile[32][257];                 // 33 KB (weight phase)
    __shared__ short AH[32][C_DIM], AL[32][C_DIM];   // 32 KB
    __shared__ short BH[32][C_DIM], BL[32][C_DIM];   // 32 KB
    __shared__ int   eij2[32][2];
    __shared__ int   inst[1024];
    __shared__ int   cntot;
    __shared__ float out32[32];
    const int bid = blockIdx.x;
    const int t = threadIdx.x;
    const int lane = t & 63, wq = t >> 6;
    const int fr = lane & 15, q = lane >> 4;
    const int et = t >> 5;                // owned edge for xcn regs
    const int c8 = (t & 31) << 3;         // owned 8-col group
    unsigned* wctr = ctrs;
    unsigned* bctr = ctrs + 1;

    if (t < 32) {
        eij2[t][0] = tar[(bid << 5) + t];
        eij2[t][1] = tar[E_EDGES + (bid << 5) + t];
        out32[t] = 0.f;
    }
    if (t == 0) cntot = 0;

    // ================= stage W: weight tile (blocks 0..47) ================
    if (bid < 48) {
        const int g  = bid >> 3;
        const int kf = bid & 7;
        const float* W = wp.p[g];
        #pragma unroll
        for (int p = 0; p < 2; ++p) {
            int s = t + (p << 10);                // 2048 float4 slots
            int row = s >> 6, c4 = s & 63;
            float4 v = *(const float4*)&W[(size_t)(kf * 32 + row) * C_DIM + (c4 << 2)];
            wtile[row][(c4 << 2) + 0] = v.x; wtile[row][(c4 << 2) + 1] = v.y;
            wtile[row][(c4 << 2) + 2] = v.z; wtile[row][(c4 << 2) + 3] = v.w;
        }
        __syncthreads();
        {
            int nf = t >> 6, ln = t & 63;         // 1024 (nf,lane) slots
            int qq = ln >> 4, ff = ln & 15;
            short h[8], lx;
            #pragma unroll
            for (int e = 0; e < 8; ++e)
                split2(wtile[qq * 8 + e][nf * 16 + ff], h[e], lx);
            int dst = (g << 16) + (((kf * 16 + nf) << 6) + ln) * 8;
            *(short4*)&WFH[dst]     = make_short4(h[0], h[1], h[2], h[3]);
            *(short4*)&WFH[dst + 4] = make_short4(h[4], h[5], h[6], h[7]);
        }
        block_signal(wctr);
    }

    // ================= stage B: bitmask slice (all blocks) ================
    {
        // block owns contiguous 4096 words; wave owns contiguous 256 words.
        const int gw = (bid << 4) + wq;           // 0..4095
        const int w0 = gw << 8;
        for (int it = 0; it < 32; ++it) {
            const int w = w0 + (it << 3);
            float v[8];
            #pragma unroll
            for (int r = 0; r < 8; ++r)
                v[r] = adj[((size_t)(w + r) << 6) + lane];
            unsigned long long m[8];
            #pragma unroll
            for (int r = 0; r < 8; ++r)
                m[r] = __ballot(v[r] > 0.5f);
            if (lane == 0) {
                #pragma unroll
                for (int r = 0; r < 4; ++r) {
                    ulonglong2 u2; u2.x = m[2 * r]; u2.y = m[2 * r + 1];
                    *(ulonglong2*)&bits[w + 2 * r] = u2;
                }
            }
        }
        block_signal(bctr);
    }

    // ================= P1: xij -> B planes (no cross-block deps) ==========
    #pragma unroll
    for (int p = 0; p < 8; ++p) {
        int idx = (p << 10) + t;
        int e = idx >> 8, c = idx & 255;
        float v = x[(size_t)eij2[e][0] * C_DIM + c] * x[(size_t)eij2[e][1] * C_DIM + c];
        short h, l;
        split2(v, h, l);
        int cw = (((c >> 3) ^ (e & 7)) << 3) + (c & 7);
        BH[e][cw] = h;
        BL[e][cw] = l;
    }
    __syncthreads();

    // ================= P2: XIJ layer B -> regs (needs all weights) ========
    block_wait(wctr, 48);
    float xijr[2][4];
    {
        f32x4 acc[2];
        layer_core(BH, BL, WFH + 2 * 65536, acc);
        const int col = (wq << 4) + fr;
        const float bb = bxij[col];
        #pragma unroll
        for (int mf = 0; mf < 2; ++mf)
            #pragma unroll
            for (int r = 0; r < 4; ++r)
                xijr[mf][r] = fmaxf(acc[mf][r] + bb, 0.f);
    }

    // ================= wait bits, then CN scan ============================
    block_wait(bctr, 256);
    {
        const int le = t >> 5, sub = t & 31;
        const size_t bi = (size_t)eij2[le][0] * 128;
        const size_t bj = (size_t)eij2[le][1] * 128;
        #pragma unroll
        for (int w4 = 0; w4 < 4; ++w4) {
            const int w = (sub << 2) + w4;
            unsigned long long m = bits[bi + w] & bits[bj + w];
            while (m) {
                int b = __builtin_ctzll(m);
                int slot = atomicAdd(&cntot, 1);
                if (slot < 1024) inst[slot] = (le << 16) | ((w << 6) + b);
                m &= m - 1;
            }
        }
    }
    __syncthreads();

    // ================= P3: on-demand H chunks -> xcnreg ===================
    float xcnreg[8];
    #pragma unroll
    for (int u = 0; u < 8; ++u) xcnreg[u] = 0.f;
    const int ctot = min(cntot, 1024);
    for (int c0 = 0; c0 < ctot; c0 += 32) {
        const int nrows = min(32, ctot - c0);
        #pragma unroll
        for (int p = 0; p < 8; ++p) {
            int idx = (p << 10) + t;
            int r = idx >> 8, c = idx & 255;
            float v = 0.f;
            if (r < nrows) {
                int k = inst[c0 + r] & 0xffff;
                v = x[(size_t)k * C_DIM + c];
            }
            short h, l;
            split2(v, h, l);
            int cw = (((c >> 3) ^ (r & 7)) << 3) + (c & 7);
            AH[r][cw] = h;
            AL[r][cw] = l;
        }
        __syncthreads();
        // T1 = relu(xk @ xlin_w1 + b1) : A -> B
        {
            f32x4 acc[2];
            layer_core(AH, AL, WFH + 0 * 65536, acc);
            const int col = (wq << 4) + fr;
            const float bb = b1x[col];
            #pragma unroll
            for (int mf = 0; mf < 2; ++mf)
                #pragma unroll
                for (int r = 0; r < 4; ++r) {
                    const int row = mf * 16 + q * 4 + r;
                    float v = fmaxf(acc[mf][r] + bb, 0.f);
                    short h, l;
                    split2(v, h, l);
                    const int cw = (((col >> 3) ^ (row & 7)) << 3) + (col & 7);
                    BH[row][cw] = h;
                    BL[row][cw] = l;
                }
        }
        __syncthreads();
        // H = relu(T1 @ xlin_w2 + b2) + x[k] : B -> A (split rows)
        {
            f32x4 acc[2];
            layer_core(BH, BL, WFH + 1 * 65536, acc);
            const int col = (wq << 4) + fr;
            const float bb = b2x[col];
            #pragma unroll
            for (int mf = 0; mf < 2; ++mf)
                #pragma unroll
                for (int r = 0; r < 4; ++r) {
                    const int row = mf * 16 + q * 4 + r;
                    if (row < nrows) {
                        const int k = inst[c0 + row] & 0xffff;
                        float v = fmaxf(acc[mf][r] + bb, 0.f) +
                                  x[(size_t)k * C_DIM + col];
                        short h, l;
                        split2(v, h, l);
                        const int cw = (((col >> 3) ^ (row & 7)) << 3) + (col & 7);
                        AH[row][cw] = h;
                        AL[row][cw] = l;
                    }
                }
        }
        __syncthreads();
        // reduce: A instance rows -> xcnreg (thread owns edge et, cols c8..+7)
        for (int s = 0; s < nrows; ++s) {
            int pk = inst[c0 + s];
            if ((pk >> 16) == et) {
                const int cw = ((c8 >> 3) ^ (s & 7)) << 3;
                short4 h0 = *(const short4*)&AH[s][cw];
                short4 h1 = *(const short4*)&AH[s][cw + 4];
                short4 l0 = *(const short4*)&AL[s][cw];
                short4 l1 = *(const short4*)&AL[s][cw + 4];
                #define BF(hh) __uint_as_float(((unsigned)(unsigned short)(hh)) << 16)
                xcnreg[0] += BF(h0.x) + BF(l0.x);
                xcnreg[1] += BF(h0.y) + BF(l0.y);
                xcnreg[2] += BF(h0.z) + BF(l0.z);
                xcnreg[3] += BF(h0.w) + BF(l0.w);
                xcnreg[4] += BF(h1.x) + BF(l1.x);
                xcnreg[5] += BF(h1.y) + BF(l1.y);
                xcnreg[6] += BF(h1.z) + BF(l1.z);
                xcnreg[7] += BF(h1.w) + BF(l1.w);
                #undef BF
            }
        }
        __syncthreads();
    }

    // ================= P4: xcnreg -> A planes =============================
    {
        const int cwb = ((c8 >> 3) ^ (et & 7)) << 3;
        short h[8], l[8];
        #pragma unroll
        for (int u = 0; u < 8; ++u) split2(xcnreg[u], h[u], l[u]);
        *(short4*)&AH[et][cwb]     = make_short4(h[0], h[1], h[2], h[3]);
        *(short4*)&AH[et][cwb + 4] = make_short4(h[4], h[5], h[6], h[7]);
        *(short4*)&AL[et][cwb]     = make_short4(l[0], l[1], l[2], l[3]);
        *(short4*)&AL[et][cwb + 4] = make_short4(l[4], l[5], l[6], l[7]);
    }
    __syncthreads();

    const float beta = betap[0];
    // ================= P5: T2 = relu(xcn @ xcn_w1 + b) : A -> B ===========
    {
        f32x4 acc[2];
        layer_core(AH, AL, WFH + 3 * 65536, acc);
        const int col = (wq << 4) + fr;
        const float bb = bcn1[col];
        #pragma unroll
        for (int mf = 0; mf < 2; ++mf)
            #pragma unroll
            for (int r = 0; r < 4; ++r) {
                const int row = mf * 16 + q * 4 + r;
                float v = fmaxf(acc[mf][r] + bb, 0.f);
                short h, l;
                split2(v, h, l);
                const int cw = (((col >> 3) ^ (row & 7)) << 3) + (col & 7);
                BH[row][cw] = h;
                BL[row][cw] = l;
            }
    }
    __syncthreads();
    // ================= P6: z = relu(T2 @ xcn_w2 + b)*beta + xijr : B -> A ==
    {
        f32x4 acc[2];
        layer_core(BH, BL, WFH + 4 * 65536, acc);
        const int col = (wq << 4) + fr;
        const float bb = bcn2[col];
        #pragma unroll
        for (int mf = 0; mf < 2; ++mf)
            #pragma unroll
            for (int r = 0; r < 4; ++r) {
                const int row = mf * 16 + q * 4 + r;
                float v = fmaxf(acc[mf][r] + bb, 0.f) * beta + xijr[mf][r];
                short h, l;
                split2(v, h, l);
                const int cw = (((col >> 3) ^ (row & 7)) << 3) + (col & 7);
                AH[row][cw] = h;
                AL[row][cw] = l;
            }
    }
    __syncthreads();
    // ================= P7: out = relu(z @ lin_w1 + b) @ w2 ================
    {
        f32x4 acc[2];
        layer_core(AH, AL, WFH + 5 * 65536, acc);
        const int col = (wq << 4) + fr;
        const float bb = blin1[col];
        const float w2c = w2[col];
        #pragma unroll
        for (int mf = 0; mf < 2; ++mf) {
            #pragma unroll
            for (int r = 0; r < 4; ++r) {
                float s = fmaxf(acc[mf][r] + bb, 0.f) * w2c;
                s += __shfl_xor(s, 1); s += __shfl_xor(s, 2);
                s += __shfl_xor(s, 4); s += __shfl_xor(s, 8);
                if (fr == 0) atomicAdd(&out32[mf * 16 + q * 4 + r], s);
            }
        }
    }
    __syncthreads();
    if (t < 32) out[(bid << 5) + t] = out32[t] + b2o[0];
}

extern "C" void kernel_launch(void* const* d_in, const int* in_sizes, int n_in,
                              void* d_out, int out_size, void* d_ws, size_t ws_size,
                              hipStream_t stream) {
    const float* x       = (const float*)d_in[0];
    const float* adj     = (const float*)d_in[1];
    const int*   tar_ei  = (const int*)  d_in[2];
    const float* xlin_w1 = (const float*)d_in[3];
    const float* xlin_b1 = (const float*)d_in[4];
    const float* xlin_w2 = (const float*)d_in[5];
    const float* xlin_b2 = (const float*)d_in[6];
    const float* xcn_w1  = (const float*)d_in[7];
    const float* xcn_b1  = (const float*)d_in[8];
    const float* xcn_w2  = (const float*)d_in[9];
    const float* xcn_b2  = (const float*)d_in[10];
    const float* xij_w   = (const float*)d_in[11];
    const float* xij_b   = (const float*)d_in[12];
    const float* lin_w1  = (const float*)d_in[13];
    const float* lin_b1  = (const float*)d_in[14];
    const float* lin_w2  = (const float*)d_in[15];
    const float* lin_b2  = (const float*)d_in[16];
    const float* beta    = (const float*)d_in[17];
    float* out = (float*)d_out;

    char* ws = (char*)d_ws;
    const size_t MB = 1024 * 1024;
    unsigned long long* bits = (unsigned long long*)(ws);       // 8 MB
    short*    WFH  = (short*)(ws + 8 * MB);                     // 768 KB
    unsigned* ctrs = (unsigned*)(ws + 9 * MB);                  // 2 x u32

    WPtrs wp;
    wp.p[0] = xlin_w1; wp.p[1] = xlin_w2; wp.p[2] = xij_w;
    wp.p[3] = xcn_w1;  wp.p[4] = xcn_w2;  wp.p[5] = lin_w1;

    hipMemsetAsync(ctrs, 0, 2 * sizeof(unsigned), stream);
    hipLaunchKernelGGL(k_all, dim3(256), dim3(1024), 0, stream,
                       adj, x, tar_ei, wp, bits, WFH, ctrs,
                       xlin_b1, xlin_b2, xij_b, xcn_b1, xcn_b2, lin_b1,
                       beta, lin_w2, lin_b2, out);
}

// Round 15
// 127.834 us; speedup vs baseline: 1.8987x; 1.8987x over previous
//
#include <hip/hip_runtime.h>
#include <cstdint>
#include <cstddef>

// CNLinkPredictor on MI355X — round 15: revert to r13 two-kernel structure
// (single-kernel grid sync = 3-4x regression, confirmed twice r7/r14).
// Edge kernel re-tiled: 16 edges/block, 512 blocks x 512 thr, LDS ~35 KB
// -> 4 blocks/CU co-resident (32 waves/CU) so phase/barrier latency of one
// block hides under compute of the others. Per-edge math identical.
//   k_prep (2096 blocks): 48 weight blocks -> frag-major split planes;
//                         2048 bitmask blocks (ballot, coalesced 256B).
//   k_edge (512 blocks, 512 thr, 8 waves): per 16-edge block:
//     P1 xij->B + CN scan; P2 XIJ->regs; P3 on-demand H chunks (<=16 rows);
//     P4 xcnreg->A; P5 T2; P6 z=relu*beta+xijr; P7 lin1+gemv -> out.
// Math = r13: split-bf16 activations x bf16-hi weights (2 MFMAs/pair),
// absmax 1.95e-3 (thr 9.77e-3). Wave = 16 rows x 32 cols (nf = 2wq+nl).
// LDS planes [16][256], chunk-XOR swizzle (c8 ^= row&7); weights frag-major
// in global (L2-resident), one 16B load/lane/frag.

#define C_DIM   256
#define N_NODES 8192
#define E_EDGES 8192

typedef short bf16x8 __attribute__((ext_vector_type(8)));
typedef float f32x4  __attribute__((ext_vector_type(4)));

struct WPtrs { const float* p[6]; };

__device__ __forceinline__ unsigned short bf16_rne(float a) {
    unsigned u = __float_as_uint(a);
    u += 0x7FFFu + ((u >> 16) & 1u);
    return (unsigned short)(u >> 16);
}
__device__ __forceinline__ void split2(float v, short& h, short& l) {
    unsigned short hb = bf16_rne(v);
    h = (short)hb;
    l = (short)bf16_rne(v - __uint_as_float((unsigned)hb << 16));
}
__device__ __forceinline__ float bf2f(short h) {
    return __uint_as_float(((unsigned)(unsigned short)h) << 16);
}

// ---------------- prep: weights (blocks 0..47) + bitmask (blocks 48..) ------
__global__ __launch_bounds__(256) void k_prep(const float* __restrict__ adj,
                                              unsigned long long* __restrict__ bits,
                                              WPtrs wp, short* __restrict__ WFH,
                                              short* __restrict__ WFL) {
    const int t = threadIdx.x;
    if (blockIdx.x < 48) {
        __shared__ float tile[32][257];
        const int g  = blockIdx.x >> 3;
        const int kf = blockIdx.x & 7;
        const float* W = wp.p[g];
        #pragma unroll
        for (int p = 0; p < 8; ++p) {
            int s = t + (p << 8);
            int row = s >> 6, c4 = s & 63;
            float4 v = *(const float4*)&W[(size_t)(kf * 32 + row) * C_DIM + (c4 << 2)];
            tile[row][(c4 << 2) + 0] = v.x; tile[row][(c4 << 2) + 1] = v.y;
            tile[row][(c4 << 2) + 2] = v.z; tile[row][(c4 << 2) + 3] = v.w;
        }
        __syncthreads();
        #pragma unroll
        for (int p = 0; p < 4; ++p) {
            int s = t + (p << 8);
            int nf = s >> 6, lane = s & 63;
            int q = lane >> 4, fr = lane & 15;
            short h[8], l[8];
            #pragma unroll
            for (int e = 0; e < 8; ++e)
                split2(tile[q * 8 + e][nf * 16 + fr], h[e], l[e]);
            int dst = (g << 16) + (((kf * 16 + nf) << 6) + lane) * 8;
            *(short4*)&WFH[dst]     = make_short4(h[0], h[1], h[2], h[3]);
            *(short4*)&WFH[dst + 4] = make_short4(h[4], h[5], h[6], h[7]);
            *(short4*)&WFL[dst]     = make_short4(l[0], l[1], l[2], l[3]);
            *(short4*)&WFL[dst + 4] = make_short4(l[4], l[5], l[6], l[7]);
        }
    } else {
        const int TOTALW = N_NODES * N_NODES / 64;        // 1M words
        const int gw   = ((int)blockIdx.x - 48) * 4 + (t >> 6);   // 0..8191
        const int lane = t & 63;
        const int NW   = 2048 * 4;
        for (int w = gw << 3; w < TOTALW; w += NW << 3) {
            float v[8];
            #pragma unroll
            for (int r = 0; r < 8; ++r)
                v[r] = adj[((size_t)(w + r) << 6) + lane];
            unsigned long long m[8];
            #pragma unroll
            for (int r = 0; r < 8; ++r)
                m[r] = __ballot(v[r] > 0.5f);
            if (lane == 0) {
                #pragma unroll
                for (int r = 0; r < 4; ++r) {
                    ulonglong2 u2; u2.x = m[2 * r]; u2.y = m[2 * r + 1];
                    *(ulonglong2*)&bits[w + 2 * r] = u2;
                }
            }
        }
    }
}

// ---- split-act x bf16-hi-weight layer core (16-row tile, 8 waves) ----
// wave wq owns nf = {2wq, 2wq+1}; acc[nl] = IN(16x256) @ Whi[:, nf*16..]
__device__ __forceinline__ void layer_core(
    const short (*INH)[C_DIM], const short (*INL)[C_DIM],
    const short* __restrict__ WH, f32x4 acc[2])
{
    const int t = threadIdx.x, lane = t & 63, wq = t >> 6;   // 8 waves
    const int fr = lane & 15, q = lane >> 4;
    #pragma unroll
    for (int i = 0; i < 2; ++i)
        #pragma unroll
        for (int r = 0; r < 4; ++r) acc[i][r] = 0.f;
    #pragma unroll 2
    for (int kf = 0; kf < 8; ++kf) {
        const int cc = (((kf << 2) + q) ^ (fr & 7)) << 3;
        bf16x8 aH = *(const bf16x8*)&INH[fr][cc];
        bf16x8 aL = *(const bf16x8*)&INL[fr][cc];
        #pragma unroll
        for (int nl = 0; nl < 2; ++nl) {
            const int nf = (wq << 1) + nl;
            const int wo = (((kf << 4) + nf) * 64 + lane) * 8;
            bf16x8 bH = *(const bf16x8*)&WH[wo];
            acc[nl] = __builtin_amdgcn_mfma_f32_16x16x32_bf16(aH, bH, acc[nl], 0, 0, 0);
            acc[nl] = __builtin_amdgcn_mfma_f32_16x16x32_bf16(aL, bH, acc[nl], 0, 0, 0);
        }
    }
}

// ---------------- edge kernel: 16 edges/block, 512 thr, 4 blocks/CU ---------
__global__ __launch_bounds__(512, 8) void k_edge(
    const unsigned long long* __restrict__ bits, const float* __restrict__ x,
    const int* __restrict__ tar,
    const short* __restrict__ WFH,
    const float* __restrict__ b1x, const float* __restrict__ b2x,
    const float* __restrict__ bxij, const float* __restrict__ bcn1,
    const float* __restrict__ bcn2, const float* __restrict__ blin1,
    const float* __restrict__ betap, const float* __restrict__ w2,
    const float* __restrict__ b2o, float* __restrict__ out)
{
    __shared__ short AH[16][C_DIM], AL[16][C_DIM];   // 16 KB
    __shared__ short BH[16][C_DIM], BL[16][C_DIM];   // 16 KB
    __shared__ int   eij2[16][2];
    __shared__ int   inst[512];
    __shared__ int   cntot;
    __shared__ float out16[16];
    const int e0 = blockIdx.x << 4;
    const int t = threadIdx.x;
    const int lane = t & 63, wq = t >> 6;
    const int fr = lane & 15, q = lane >> 4;
    const int et = t >> 5;                // owned edge (0..15)
    const int c8 = (t & 31) << 3;         // owned 8-col group

    if (t < 16) {
        eij2[t][0] = tar[e0 + t];
        eij2[t][1] = tar[E_EDGES + e0 + t];
        out16[t] = 0.f;
    }
    if (t == 0) cntot = 0;
    __syncthreads();

    // ---- P1: xij -> B planes + CN bit-scan (merged) ----
    #pragma unroll
    for (int p = 0; p < 8; ++p) {
        int idx = (p << 9) + t;
        int e = idx >> 8, c = idx & 255;
        float v = x[(size_t)eij2[e][0] * C_DIM + c] * x[(size_t)eij2[e][1] * C_DIM + c];
        short h, l;
        split2(v, h, l);
        int cw = (((c >> 3) ^ (e & 7)) << 3) + (c & 7);
        BH[e][cw] = h;
        BL[e][cw] = l;
    }
    {
        const int le = t >> 5, sub = t & 31;
        const size_t bi = (size_t)eij2[le][0] * 128;
        const size_t bj = (size_t)eij2[le][1] * 128;
        #pragma unroll
        for (int w4 = 0; w4 < 4; ++w4) {
            const int w = (sub << 2) + w4;
            unsigned long long m = bits[bi + w] & bits[bj + w];
            while (m) {
                int b = __builtin_ctzll(m);
                int slot = atomicAdd(&cntot, 1);
                if (slot < 512) inst[slot] = (le << 16) | ((w << 6) + b);
                m &= m - 1;
            }
        }
    }
    __syncthreads();

    // ---- P2: XIJ layer B -> registers ----
    float xijr[2][4];
    {
        f32x4 acc[2];
        layer_core(BH, BL, WFH + 2 * 65536, acc);
        #pragma unroll
        for (int nl = 0; nl < 2; ++nl) {
            const int col = ((wq << 1) + nl) * 16 + fr;
            const float bb = bxij[col];
            #pragma unroll
            for (int r = 0; r < 4; ++r)
                xijr[nl][r] = fmaxf(acc[nl][r] + bb, 0.f);
        }
    }

    // ---- P3: on-demand H chunks (<=16 rows) -> xcnreg ----
    float xcnreg[8];
    #pragma unroll
    for (int u = 0; u < 8; ++u) xcnreg[u] = 0.f;
    const int ctot = min(cntot, 512);
    for (int c0 = 0; c0 < ctot; c0 += 16) {
        const int nrows = min(16, ctot - c0);
        #pragma unroll
        for (int p = 0; p < 8; ++p) {
            int idx = (p << 9) + t;
            int r = idx >> 8, c = idx & 255;
            float v = 0.f;
            if (r < nrows) {
                int k = inst[c0 + r] & 0xffff;
                v = x[(size_t)k * C_DIM + c];
            }
            short h, l;
            split2(v, h, l);
            int cw = (((c >> 3) ^ (r & 7)) << 3) + (c & 7);
            AH[r][cw] = h;
            AL[r][cw] = l;
        }
        __syncthreads();
        // T1 = relu(xk @ xlin_w1 + b1) : A -> B
        {
            f32x4 acc[2];
            layer_core(AH, AL, WFH + 0 * 65536, acc);
            #pragma unroll
            for (int nl = 0; nl < 2; ++nl) {
                const int col = ((wq << 1) + nl) * 16 + fr;
                const float bb = b1x[col];
                #pragma unroll
                for (int r = 0; r < 4; ++r) {
                    const int row = q * 4 + r;
                    float v = fmaxf(acc[nl][r] + bb, 0.f);
                    short h, l;
                    split2(v, h, l);
                    const int cw = (((col >> 3) ^ (row & 7)) << 3) + (col & 7);
                    BH[row][cw] = h;
                    BL[row][cw] = l;
                }
            }
        }
        __syncthreads();
        // H = relu(T1 @ xlin_w2 + b2) + x[k] : B -> A (split rows)
        {
            f32x4 acc[2];
            layer_core(BH, BL, WFH + 1 * 65536, acc);
            #pragma unroll
            for (int nl = 0; nl < 2; ++nl) {
                const int col = ((wq << 1) + nl) * 16 + fr;
                const float bb = b2x[col];
                #pragma unroll
                for (int r = 0; r < 4; ++r) {
                    const int row = q * 4 + r;
                    if (row < nrows) {
                        const int k = inst[c0 + row] & 0xffff;
                        float v = fmaxf(acc[nl][r] + bb, 0.f) +
                                  x[(size_t)k * C_DIM + col];
                        short h, l;
                        split2(v, h, l);
                        const int cw = (((col >> 3) ^ (row & 7)) << 3) + (col & 7);
                        AH[row][cw] = h;
                        AL[row][cw] = l;
                    }
                }
            }
        }
        __syncthreads();
        // reduce: A instance rows -> xcnreg (thread owns edge et, cols c8..+7)
        for (int s = 0; s < nrows; ++s) {
            int pk = inst[c0 + s];
            if ((pk >> 16) == et) {
                const int cw = ((c8 >> 3) ^ (s & 7)) << 3;
                short4 h0 = *(const short4*)&AH[s][cw];
                short4 h1 = *(const short4*)&AH[s][cw + 4];
                short4 l0 = *(const short4*)&AL[s][cw];
                short4 l1 = *(const short4*)&AL[s][cw + 4];
                xcnreg[0] += bf2f(h0.x) + bf2f(l0.x);
                xcnreg[1] += bf2f(h0.y) + bf2f(l0.y);
                xcnreg[2] += bf2f(h0.z) + bf2f(l0.z);
                xcnreg[3] += bf2f(h0.w) + bf2f(l0.w);
                xcnreg[4] += bf2f(h1.x) + bf2f(l1.x);
                xcnreg[5] += bf2f(h1.y) + bf2f(l1.y);
                xcnreg[6] += bf2f(h1.z) + bf2f(l1.z);
                xcnreg[7] += bf2f(h1.w) + bf2f(l1.w);
            }
        }
        __syncthreads();
    }

    // ---- P4: xcnreg -> A planes ----
    {
        const int cwb = ((c8 >> 3) ^ (et & 7)) << 3;
        short h[8], l[8];
        #pragma unroll
        for (int u = 0; u < 8; ++u) split2(xcnreg[u], h[u], l[u]);
        *(short4*)&AH[et][cwb]     = make_short4(h[0], h[1], h[2], h[3]);
        *(short4*)&AH[et][cwb + 4] = make_short4(h[4], h[5], h[6], h[7]);
        *(short4*)&AL[et][cwb]     = make_short4(l[0], l[1], l[2], l[3]);
        *(short4*)&AL[et][cwb + 4] = make_short4(l[4], l[5], l[6], l[7]);
    }
    __syncthreads();

    const float beta = betap[0];
    // ---- P5: T2 = relu(xcn @ xcn_w1 + b) : A -> B ----
    {
        f32x4 acc[2];
        layer_core(AH, AL, WFH + 3 * 65536, acc);
        #pragma unroll
        for (int nl = 0; nl < 2; ++nl) {
            const int col = ((wq << 1) + nl) * 16 + fr;
            const float bb = bcn1[col];
            #pragma unroll
            for (int r = 0; r < 4; ++r) {
                const int row = q * 4 + r;
                float v = fmaxf(acc[nl][r] + bb, 0.f);
                short h, l;
                split2(v, h, l);
                const int cw = (((col >> 3) ^ (row & 7)) << 3) + (col & 7);
                BH[row][cw] = h;
                BL[row][cw] = l;
            }
        }
    }
    __syncthreads();
    // ---- P6: z = relu(T2 @ xcn_w2 + b)*beta + XIJ(regs) : B -> A ----
    {
        f32x4 acc[2];
        layer_core(BH, BL, WFH + 4 * 65536, acc);
        #pragma unroll
        for (int nl = 0; nl < 2; ++nl) {
            const int col = ((wq << 1) + nl) * 16 + fr;
            const float bb = bcn2[col];
            #pragma unroll
            for (int r = 0; r < 4; ++r) {
                const int row = q * 4 + r;
                float v = fmaxf(acc[nl][r] + bb, 0.f) * beta + xijr[nl][r];
                short h, l;
                split2(v, h, l);
                const int cw = (((col >> 3) ^ (row & 7)) << 3) + (col & 7);
                AH[row][cw] = h;
                AL[row][cw] = l;
            }
        }
    }
    __syncthreads();
    // ---- P7: out = relu(z @ lin_w1 + b) @ w2 (gemv fused) ----
    {
        f32x4 acc[2];
        layer_core(AH, AL, WFH + 5 * 65536, acc);
        #pragma unroll
        for (int nl = 0; nl < 2; ++nl) {
            const int col = ((wq << 1) + nl) * 16 + fr;
            const float bb = blin1[col];
            const float w2c = w2[col];
            #pragma unroll
            for (int r = 0; r < 4; ++r) {
                float s = fmaxf(acc[nl][r] + bb, 0.f) * w2c;
                s += __shfl_xor(s, 1); s += __shfl_xor(s, 2);
                s += __shfl_xor(s, 4); s += __shfl_xor(s, 8);
                if (fr == 0) atomicAdd(&out16[q * 4 + r], s);
            }
        }
    }
    __syncthreads();
    if (t < 16) out[e0 + t] = out16[t] + b2o[0];
}

extern "C" void kernel_launch(void* const* d_in, const int* in_sizes, int n_in,
                              void* d_out, int out_size, void* d_ws, size_t ws_size,
                              hipStream_t stream) {
    const float* x       = (const float*)d_in[0];
    const float* adj     = (const float*)d_in[1];
    const int*   tar_ei  = (const int*)  d_in[2];
    const float* xlin_w1 = (const float*)d_in[3];
    const float* xlin_b1 = (const float*)d_in[4];
    const float* xlin_w2 = (const float*)d_in[5];
    const float* xlin_b2 = (const float*)d_in[6];
    const float* xcn_w1  = (const float*)d_in[7];
    const float* xcn_b1  = (const float*)d_in[8];
    const float* xcn_w2  = (const float*)d_in[9];
    const float* xcn_b2  = (const float*)d_in[10];
    const float* xij_w   = (const float*)d_in[11];
    const float* xij_b   = (const float*)d_in[12];
    const float* lin_w1  = (const float*)d_in[13];
    const float* lin_b1  = (const float*)d_in[14];
    const float* lin_w2  = (const float*)d_in[15];
    const float* lin_b2  = (const float*)d_in[16];
    const float* beta    = (const float*)d_in[17];
    float* out = (float*)d_out;

    char* ws = (char*)d_ws;
    const size_t MB = 1024 * 1024;
    unsigned long long* bits = (unsigned long long*)(ws);       // 8 MB
    short* WFH  = (short*)(ws +  8 * MB);   // 768 KB
    short* WFL  = (short*)(ws +  9 * MB);   // 768 KB

    WPtrs wp;
    wp.p[0] = xlin_w1; wp.p[1] = xlin_w2; wp.p[2] = xij_w;
    wp.p[3] = xcn_w1;  wp.p[4] = xcn_w2;  wp.p[5] = lin_w1;

    hipLaunchKernelGGL(k_prep, dim3(48 + 2048), dim3(256), 0, stream,
                       adj, bits, wp, WFH, WFL);
    hipLaunchKernelGGL(k_edge, dim3(E_EDGES / 16), dim3(512), 0, stream,
                       bits, x, tar_ei, WFH,
                       xlin_b1, xlin_b2, xij_b, xcn_b1, xcn_b2, lin_b1,
                       beta, lin_w2, lin_b2, out);
}

// Round 16
// 78.127 us; speedup vs baseline: 3.1068x; 1.6362x over previous
//
#include <hip/hip_runtime.h>
#include <cstdint>
#include <cstddef>

// CNLinkPredictor on MI355X — round 16: revert to r13 (best, 79.2 us;
// r15's 16-edge tile doubled weight L2 traffic + VGPR cap = 128 us).
// Safe-only deltas vs r13:
//   1. WFL plane deleted (edge kernel never read it) — fewer writes/VALU.
//   2. prep grid 48+2000 = 2048 blocks = exact 8/CU co-residency (was 2096
//      -> 48-block tail). Bitmask grid-stride redistributes identically.
//   k_prep (2048 blocks): 48 weight blocks -> frag-major bf16-hi planes;
//                         2000 bitmask blocks (ballot, coalesced 256B).
//   k_edge_mega (256 blocks, 1024 thr, 16 waves): per 32-edge block:
//     P1 xij->B + CN scan; P2 XIJ->regs; P3 on-demand H chunks
//     (T1, H=relu(T1@w2)+x[k], reduce->xcnreg); P4 xcnreg->A; P5 T2;
//     P6 z=relu*beta+xijr; P7 lin1+gemv -> out.
// Math: split-bf16 activations x bf16-hi weights (2 MFMAs/pair),
// absmax 1.95e-3 (threshold 9.77e-3). LDS planes [32][256] chunk-XOR
// swizzle (c8 ^= row&7); weights frag-major, one 16B load/lane/frag.

#define C_DIM   256
#define N_NODES 8192
#define E_EDGES 8192

typedef short bf16x8 __attribute__((ext_vector_type(8)));
typedef float f32x4  __attribute__((ext_vector_type(4)));

struct WPtrs { const float* p[6]; };

__device__ __forceinline__ unsigned short bf16_rne(float a) {
    unsigned u = __float_as_uint(a);
    u += 0x7FFFu + ((u >> 16) & 1u);
    return (unsigned short)(u >> 16);
}
__device__ __forceinline__ void split2(float v, short& h, short& l) {
    unsigned short hb = bf16_rne(v);
    h = (short)hb;
    l = (short)bf16_rne(v - __uint_as_float((unsigned)hb << 16));
}
__device__ __forceinline__ float bf2f(short h) {
    return __uint_as_float(((unsigned)(unsigned short)h) << 16);
}

// ---------------- prep: weights (blocks 0..47) + bitmask (blocks 48..2047) --
__global__ __launch_bounds__(256) void k_prep(const float* __restrict__ adj,
                                              unsigned long long* __restrict__ bits,
                                              WPtrs wp, short* __restrict__ WFH) {
    const int t = threadIdx.x;
    if (blockIdx.x < 48) {
        __shared__ float tile[32][257];
        const int g  = blockIdx.x >> 3;
        const int kf = blockIdx.x & 7;
        const float* W = wp.p[g];
        #pragma unroll
        for (int p = 0; p < 8; ++p) {
            int s = t + (p << 8);
            int row = s >> 6, c4 = s & 63;
            float4 v = *(const float4*)&W[(size_t)(kf * 32 + row) * C_DIM + (c4 << 2)];
            tile[row][(c4 << 2) + 0] = v.x; tile[row][(c4 << 2) + 1] = v.y;
            tile[row][(c4 << 2) + 2] = v.z; tile[row][(c4 << 2) + 3] = v.w;
        }
        __syncthreads();
        #pragma unroll
        for (int p = 0; p < 4; ++p) {
            int s = t + (p << 8);
            int nf = s >> 6, lane = s & 63;
            int q = lane >> 4, fr = lane & 15;
            short h[8];
            #pragma unroll
            for (int e = 0; e < 8; ++e)
                h[e] = (short)bf16_rne(tile[q * 8 + e][nf * 16 + fr]);
            int dst = (g << 16) + (((kf * 16 + nf) << 6) + lane) * 8;
            *(short4*)&WFH[dst]     = make_short4(h[0], h[1], h[2], h[3]);
            *(short4*)&WFH[dst + 4] = make_short4(h[4], h[5], h[6], h[7]);
        }
    } else {
        const int TOTALW = N_NODES * N_NODES / 64;        // 1M words
        const int gw   = ((int)blockIdx.x - 48) * 4 + (t >> 6);   // 0..7999
        const int lane = t & 63;
        const int NW   = 2000 * 4;                         // 8000 waves
        for (int w = gw << 3; w < TOTALW; w += NW << 3) {
            float v[8];
            #pragma unroll
            for (int r = 0; r < 8; ++r)
                v[r] = adj[((size_t)(w + r) << 6) + lane];
            unsigned long long m[8];
            #pragma unroll
            for (int r = 0; r < 8; ++r)
                m[r] = __ballot(v[r] > 0.5f);
            if (lane == 0) {
                #pragma unroll
                for (int r = 0; r < 4; ++r) {
                    ulonglong2 u2; u2.x = m[2 * r]; u2.y = m[2 * r + 1];
                    *(ulonglong2*)&bits[w + 2 * r] = u2;
                }
            }
        }
    }
}

// ---- split-act x bf16-hi-weight layer core: acc[2] = IN(32x256) @ Whi ----
__device__ __forceinline__ void layer_core(
    const short (*INH)[C_DIM], const short (*INL)[C_DIM],
    const short* __restrict__ WH, f32x4 acc[2])
{
    const int t = threadIdx.x, lane = t & 63, wq = t >> 6;   // 16 waves
    const int fr = lane & 15, q = lane >> 4;
    #pragma unroll
    for (int i = 0; i < 2; ++i)
        #pragma unroll
        for (int r = 0; r < 4; ++r) acc[i][r] = 0.f;
    #pragma unroll 2
    for (int kf = 0; kf < 8; ++kf) {
        bf16x8 aH[2], aL[2];
        #pragma unroll
        for (int mf = 0; mf < 2; ++mf) {
            const int row = mf * 16 + fr;
            const int cc = (((kf << 2) + q) ^ (row & 7)) << 3;
            aH[mf] = *(const bf16x8*)&INH[row][cc];
            aL[mf] = *(const bf16x8*)&INL[row][cc];
        }
        const int wo = (((kf << 4) + wq) * 64 + lane) * 8;
        bf16x8 bH = *(const bf16x8*)&WH[wo];
        #pragma unroll
        for (int mf = 0; mf < 2; ++mf) {
            acc[mf] = __builtin_amdgcn_mfma_f32_16x16x32_bf16(aH[mf], bH, acc[mf], 0, 0, 0);
            acc[mf] = __builtin_amdgcn_mfma_f32_16x16x32_bf16(aL[mf], bH, acc[mf], 0, 0, 0);
        }
    }
}

// ---------------- edge mega-kernel: 1024 threads, 16 waves ----------------
__global__ __launch_bounds__(1024, 1) void k_edge_mega(
    const unsigned long long* __restrict__ bits, const float* __restrict__ x,
    const int* __restrict__ tar,
    const short* __restrict__ WFH,
    const float* __restrict__ b1x, const float* __restrict__ b2x,
    const float* __restrict__ bxij, const float* __restrict__ bcn1,
    const float* __restrict__ bcn2, const float* __restrict__ blin1,
    const float* __restrict__ betap, const float* __restrict__ w2,
    const float* __restrict__ b2o, float* __restrict__ out)
{
    __shared__ short AH[32][C_DIM], AL[32][C_DIM];   // plane A (32 KB)
    __shared__ short BH[32][C_DIM], BL[32][C_DIM];   // plane B (32 KB)
    __shared__ int   eij2[32][2];
    __shared__ int   inst[1024];
    __shared__ int   cntot;
    __shared__ float out32[32];
    const int e0 = blockIdx.x << 5;
    const int t = threadIdx.x;
    const int lane = t & 63, wq = t >> 6;
    const int fr = lane & 15, q = lane >> 4;
    const int et = t >> 5;                // owned edge for xcn regs
    const int c8 = (t & 31) << 3;         // owned 8-col group

    if (t < 32) {
        eij2[t][0] = tar[e0 + t];
        eij2[t][1] = tar[E_EDGES + e0 + t];
        out32[t] = 0.f;
    }
    if (t == 0) cntot = 0;
    __syncthreads();

    // ---- P1: xij -> B planes  +  CN bit-scan (merged) ----
    #pragma unroll
    for (int p = 0; p < 8; ++p) {
        int idx = (p << 10) + t;
        int e = idx >> 8, c = idx & 255;
        float v = x[(size_t)eij2[e][0] * C_DIM + c] * x[(size_t)eij2[e][1] * C_DIM + c];
        short h, l;
        split2(v, h, l);
        int cw = (((c >> 3) ^ (e & 7)) << 3) + (c & 7);
        BH[e][cw] = h;
        BL[e][cw] = l;
    }
    {
        const int le = t >> 5, sub = t & 31;
        const size_t bi = (size_t)eij2[le][0] * 128;
        const size_t bj = (size_t)eij2[le][1] * 128;
        #pragma unroll
        for (int w4 = 0; w4 < 4; ++w4) {
            const int w = (sub << 2) + w4;
            unsigned long long m = bits[bi + w] & bits[bj + w];
            while (m) {
                int b = __builtin_ctzll(m);
                int slot = atomicAdd(&cntot, 1);
                if (slot < 1024) inst[slot] = (le << 16) | ((w << 6) + b);
                m &= m - 1;
            }
        }
    }
    __syncthreads();

    // ---- P2: XIJ layer B -> registers ----
    float xijr[2][4];
    {
        f32x4 acc[2];
        layer_core(BH, BL, WFH + 2 * 65536, acc);
        const int col = (wq << 4) + fr;
        const float bb = bxij[col];
        #pragma unroll
        for (int mf = 0; mf < 2; ++mf)
            #pragma unroll
            for (int r = 0; r < 4; ++r)
                xijr[mf][r] = fmaxf(acc[mf][r] + bb, 0.f);
    }

    // ---- P3: on-demand H chunks -> xcnreg ----
    float xcnreg[8];
    #pragma unroll
    for (int u = 0; u < 8; ++u) xcnreg[u] = 0.f;
    const int ctot = min(cntot, 1024);
    for (int c0 = 0; c0 < ctot; c0 += 32) {
        const int nrows = min(32, ctot - c0);
        // stage x[k] -> A
        #pragma unroll
        for (int p = 0; p < 8; ++p) {
            int idx = (p << 10) + t;
            int r = idx >> 8, c = idx & 255;
            float v = 0.f;
            if (r < nrows) {
                int k = inst[c0 + r] & 0xffff;
                v = x[(size_t)k * C_DIM + c];
            }
            short h, l;
            split2(v, h, l);
            int cw = (((c >> 3) ^ (r & 7)) << 3) + (c & 7);
            AH[r][cw] = h;
            AL[r][cw] = l;
        }
        __syncthreads();
        // T1 = relu(xk @ xlin_w1 + b1) : A -> B
        {
            f32x4 acc[2];
            layer_core(AH, AL, WFH + 0 * 65536, acc);
            const int col = (wq << 4) + fr;
            const float bb = b1x[col];
            #pragma unroll
            for (int mf = 0; mf < 2; ++mf)
                #pragma unroll
                for (int r = 0; r < 4; ++r) {
                    const int row = mf * 16 + q * 4 + r;
                    float v = fmaxf(acc[mf][r] + bb, 0.f);
                    short h, l;
                    split2(v, h, l);
                    const int cw = (((col >> 3) ^ (row & 7)) << 3) + (col & 7);
                    BH[row][cw] = h;
                    BL[row][cw] = l;
                }
        }
        __syncthreads();
        // H = relu(T1 @ xlin_w2 + b2) + x[k] : B -> A (split rows)
        {
            f32x4 acc[2];
            layer_core(BH, BL, WFH + 1 * 65536, acc);
            const int col = (wq << 4) + fr;
            const float bb = b2x[col];
            #pragma unroll
            for (int mf = 0; mf < 2; ++mf)
                #pragma unroll
                for (int r = 0; r < 4; ++r) {
                    const int row = mf * 16 + q * 4 + r;
                    if (row < nrows) {
                        const int k = inst[c0 + row] & 0xffff;
                        float v = fmaxf(acc[mf][r] + bb, 0.f) +
                                  x[(size_t)k * C_DIM + col];
                        short h, l;
                        split2(v, h, l);
                        const int cw = (((col >> 3) ^ (row & 7)) << 3) + (col & 7);
                        AH[row][cw] = h;
                        AL[row][cw] = l;
                    }
                }
        }
        __syncthreads();
        // reduce: A instance rows -> xcnreg (thread owns edge et, cols c8..+7)
        for (int s = 0; s < nrows; ++s) {
            int pk = inst[c0 + s];
            if ((pk >> 16) == et) {
                const int cw = ((c8 >> 3) ^ (s & 7)) << 3;
                short4 h0 = *(const short4*)&AH[s][cw];
                short4 h1 = *(const short4*)&AH[s][cw + 4];
                short4 l0 = *(const short4*)&AL[s][cw];
                short4 l1 = *(const short4*)&AL[s][cw + 4];
                xcnreg[0] += bf2f(h0.x) + bf2f(l0.x);
                xcnreg[1] += bf2f(h0.y) + bf2f(l0.y);
                xcnreg[2] += bf2f(h0.z) + bf2f(l0.z);
                xcnreg[3] += bf2f(h0.w) + bf2f(l0.w);
                xcnreg[4] += bf2f(h1.x) + bf2f(l1.x);
                xcnreg[5] += bf2f(h1.y) + bf2f(l1.y);
                xcnreg[6] += bf2f(h1.z) + bf2f(l1.z);
                xcnreg[7] += bf2f(h1.w) + bf2f(l1.w);
            }
        }
        __syncthreads();
    }

    // ---- P4: xcnreg -> A planes ----
    {
        const int cwb = ((c8 >> 3) ^ (et & 7)) << 3;
        short h[8], l[8];
        #pragma unroll
        for (int u = 0; u < 8; ++u) split2(xcnreg[u], h[u], l[u]);
        *(short4*)&AH[et][cwb]     = make_short4(h[0], h[1], h[2], h[3]);
        *(short4*)&AH[et][cwb + 4] = make_short4(h[4], h[5], h[6], h[7]);
        *(short4*)&AL[et][cwb]     = make_short4(l[0], l[1], l[2], l[3]);
        *(short4*)&AL[et][cwb + 4] = make_short4(l[4], l[5], l[6], l[7]);
    }
    __syncthreads();

    const float beta = betap[0];
    // ---- P5: T2 = relu(xcn @ xcn_w1 + b) : A -> B ----
    {
        f32x4 acc[2];
        layer_core(AH, AL, WFH + 3 * 65536, acc);
        const int col = (wq << 4) + fr;
        const float bb = bcn1[col];
        #pragma unroll
        for (int mf = 0; mf < 2; ++mf)
            #pragma unroll
            for (int r = 0; r < 4; ++r) {
                const int row = mf * 16 + q * 4 + r;
                float v = fmaxf(acc[mf][r] + bb, 0.f);
                short h, l;
                split2(v, h, l);
                const int cw = (((col >> 3) ^ (row & 7)) << 3) + (col & 7);
                BH[row][cw] = h;
                BL[row][cw] = l;
            }
    }
    __syncthreads();
    // ---- P6: z = relu(T2 @ xcn_w2 + b)*beta + XIJ(regs) : B -> A ----
    {
        f32x4 acc[2];
        layer_core(BH, BL, WFH + 4 * 65536, acc);
        const int col = (wq << 4) + fr;
        const float bb = bcn2[col];
        #pragma unroll
        for (int mf = 0; mf < 2; ++mf)
            #pragma unroll
            for (int r = 0; r < 4; ++r) {
                const int row = mf * 16 + q * 4 + r;
                float v = fmaxf(acc[mf][r] + bb, 0.f) * beta + xijr[mf][r];
                short h, l;
                split2(v, h, l);
                const int cw = (((col >> 3) ^ (row & 7)) << 3) + (col & 7);
                AH[row][cw] = h;
                AL[row][cw] = l;
            }
    }
    __syncthreads();
    // ---- P7: out = relu(z @ lin_w1 + b) @ w2 (gemv fused) ----
    {
        f32x4 acc[2];
        layer_core(AH, AL, WFH + 5 * 65536, acc);
        const int col = (wq << 4) + fr;
        const float bb = blin1[col];
        const float w2c = w2[col];
        #pragma unroll
        for (int mf = 0; mf < 2; ++mf) {
            #pragma unroll
            for (int r = 0; r < 4; ++r) {
                float s = fmaxf(acc[mf][r] + bb, 0.f) * w2c;
                s += __shfl_xor(s, 1); s += __shfl_xor(s, 2);
                s += __shfl_xor(s, 4); s += __shfl_xor(s, 8);
                if (fr == 0) atomicAdd(&out32[mf * 16 + q * 4 + r], s);
            }
        }
    }
    __syncthreads();
    if (t < 32) out[e0 + t] = out32[t] + b2o[0];
}

extern "C" void kernel_launch(void* const* d_in, const int* in_sizes, int n_in,
                              void* d_out, int out_size, void* d_ws, size_t ws_size,
                              hipStream_t stream) {
    const float* x       = (const float*)d_in[0];
    const float* adj     = (const float*)d_in[1];
    const int*   tar_ei  = (const int*)  d_in[2];
    const float* xlin_w1 = (const float*)d_in[3];
    const float* xlin_b1 = (const float*)d_in[4];
    const float* xlin_w2 = (const float*)d_in[5];
    const float* xlin_b2 = (const float*)d_in[6];
    const float* xcn_w1  = (const float*)d_in[7];
    const float* xcn_b1  = (const float*)d_in[8];
    const float* xcn_w2  = (const float*)d_in[9];
    const float* xcn_b2  = (const float*)d_in[10];
    const float* xij_w   = (const float*)d_in[11];
    const float* xij_b   = (const float*)d_in[12];
    const float* lin_w1  = (const float*)d_in[13];
    const float* lin_b1  = (const float*)d_in[14];
    const float* lin_w2  = (const float*)d_in[15];
    const float* lin_b2  = (const float*)d_in[16];
    const float* beta    = (const float*)d_in[17];
    float* out = (float*)d_out;

    char* ws = (char*)d_ws;
    const size_t MB = 1024 * 1024;
    unsigned long long* bits = (unsigned long long*)(ws);       // 8 MB
    short* WFH  = (short*)(ws +  8 * MB);   // 768 KB

    WPtrs wp;
    wp.p[0] = xlin_w1; wp.p[1] = xlin_w2; wp.p[2] = xij_w;
    wp.p[3] = xcn_w1;  wp.p[4] = xcn_w2;  wp.p[5] = lin_w1;

    hipLaunchKernelGGL(k_prep, dim3(48 + 2000), dim3(256), 0, stream,
                       adj, bits, wp, WFH);
    hipLaunchKernelGGL(k_edge_mega, dim3(E_EDGES / 32), dim3(1024), 0, stream,
                       bits, x, tar_ei, WFH,
                       xlin_b1, xlin_b2, xij_b, xcn_b1, xcn_b2, lin_b1,
                       beta, lin_w2, lin_b2, out);
}